// Round 13
// baseline (106.437 us; speedup 1.0000x reference)
//
#include <hip/hip_runtime.h>
#include <math.h>

// Problem constants
#define D_DOM 64
#define S_RES 512
#define R_ROWS 2048
#define NAA 20
#define NF 12
#define NB 2
#define NJ 24       // NB*NF
#define NPC 8       // p-chunks per domain (256 rows each)
#define BROWS 8     // rows per stage batch (16 KB f32, 4 p)
#define NBATCH 32   // batches per block (256 rows)
#define BSTR 512    // bf16 row stride. NO pad: 53,248 B total LDS -> 3
                    // blocks/CU (was 520/2 blocks). Accepts 4-way conflict
                    // on B-frag reads for +50% occupancy (R13).

typedef unsigned short ushort_t;
typedef unsigned int uint_t;
typedef short bf16x8 __attribute__((ext_vector_type(8)));   // 8 bf16 = 4 VGPR
typedef float f32x4 __attribute__((ext_vector_type(4)));

// bf16 helpers (RNE), dependency-free — validated R4-R12
__device__ __forceinline__ ushort_t f2bf(float x) {
  uint_t u = __float_as_uint(x);
  uint_t r = u + 0x7FFFu + ((u >> 16) & 1u);
  return (ushort_t)(r >> 16);
}
__device__ __forceinline__ float bflo(uint_t u) { return __uint_as_float(u << 16); }
__device__ __forceinline__ float bfhi(uint_t u) { return __uint_as_float(u & 0xFFFF0000u); }
__device__ __forceinline__ float bf2f(ushort_t h) {
  return __uint_as_float(((uint_t)h) << 16);
}
__device__ __forceinline__ uint_t pk2(float a, float b) {
  return (uint_t)f2bf(a) | ((uint_t)f2bf(b) << 16);
}

// Direct global->LDS DMA, 16 B/lane (dest wave-uniform base).
__device__ __forceinline__ void gload_lds16(const float* g, float* l) {
  __builtin_amdgcn_global_load_lds((const __attribute__((address_space(1))) void*)g,
                                   (__attribute__((address_space(3))) void*)l,
                                   16, 0, 0);
}

// ---------------------------------------------------------------------------
// Kernel A (R10, unchanged): G[d][j][k] bf16.
// ---------------------------------------------------------------------------
__global__ __launch_bounds__(256) void kA_g(const float* __restrict__ aa,
                                            const float* __restrict__ wconv,
                                            ushort_t* __restrict__ g) {
  __shared__ float ws[NF * NAA * 2];
  const int tid = threadIdx.x;
  for (int i = tid; i < NF * NAA * 2; i += 256) ws[i] = wconv[i];
  __syncthreads();
  const int pos = blockIdx.x * 256 + tid;  // d*512 + s
  const int b = blockIdx.y;
  float av[NAA];
#pragma unroll
  for (int c = 0; c < NAA; ++c)
    av[c] = aa[(size_t)(b * NAA + c) * (D_DOM * S_RES) + pos];
  const int d = pos >> 9;
  const int s = pos & 511;
#pragma unroll
  for (int f = 0; f < NF; ++f) {
    float s0 = 0.f, s1 = 0.f;
#pragma unroll
    for (int c = 0; c < NAA; ++c) {
      const float a = av[c];
      s0 = fmaf(a, ws[(f * NAA + c) * 2 + 0], s0);
      s1 = fmaf(a, ws[(f * NAA + c) * 2 + 1], s1);
    }
    const int j = b * NF + f;
    g[((size_t)(d * NJ + j)) * 1024 + s] = f2bf(s0);
    g[((size_t)(d * NJ + j)) * 1024 + 512 + s] = f2bf(s1);
  }
}

// ---------------------------------------------------------------------------
// Kernel B — R10 structure (94.7 us champion), BSTR 520->512 only.
// 2-barrier lagged-y pipeline; prefetch continuously in flight (R11 lesson:
// don't trade overlap for LDS-read count).
// ---------------------------------------------------------------------------
__global__ __launch_bounds__(256) void kB_main(const float* __restrict__ adjs,
                                               const ushort_t* __restrict__ g,
                                               ushort_t* __restrict__ yp,
                                               float* __restrict__ degp) {
  const int tid = threadIdx.x;
  const int w = tid >> 6;   // 0..3
  const int l = tid & 63;
  const int d = blockIdx.x >> 3;
  const int pc = blockIdx.x & 7;

  const int mt = w & 1, kh = w >> 1;
  const int jl = l & 15, kg = l >> 4;
  const int pl = jl & 3;  // B-frag p (cols 4-15 duplicate 0-3, ignored)

  __shared__ float rows[2][BROWS][S_RES];                  // 32 KB f32 (dbuf)
  __shared__ __align__(16) ushort_t Bs16[2][BROWS][BSTR];  // 16 KB (dbuf)
  __shared__ __align__(16) float hs[2][2][2][16][4];       // 4 KB

  const float* ablk = adjs + ((size_t)d * R_ROWS + (size_t)pc * 256) * S_RES;

  // A-frags: wave's (mt, kh): 16 ksteps x 8 bf16 (loop-invariant, 64 VGPR)
  bf16x8 gf[16];
  {
    const int j_a = mt * 16 + jl;
    const bool valid = (j_a < NJ);
    const ushort_t* gr =
        g + ((size_t)(d * NJ + (valid ? j_a : 0))) * 1024 + kh * 512 + kg * 8;
    const bf16x8 z = {};
#pragma unroll
    for (int ks = 0; ks < 16; ++ks) {
      bf16x8 v = *(const bf16x8*)(gr + ks * 32);
      gf[ks] = valid ? v : z;
    }
  }

  float yv[6][8];
#pragma unroll
  for (int jj = 0; jj < 6; ++jj)
#pragma unroll
    for (int e = 0; e < 8; ++e) yv[jj][e] = 0.f;
  float dgv[8];
#pragma unroll
  for (int e = 0; e < 8; ++e) dgv[e] = 0.f;

#define STAGE(T)                                                               \
  {                                                                            \
    _Pragma("unroll")                                                          \
    for (int q = 0; q < 4; ++q) {                                              \
      const int u_ = w * 4 + q;                                                \
      const int row_ = u_ >> 1;                                                \
      const int half_ = u_ & 1;                                                \
      gload_lds16(ablk + ((size_t)((T)*BROWS + row_)) * S_RES + half_ * 256 +  \
                      l * 4,                                                   \
                  &rows[(T) & 1][row_][half_ * 256]);                          \
    }                                                                          \
  }

#define Y_PHASE(TT)                                                            \
  {                                                                            \
    const int buf_ = (TT) & 1;                                                 \
    float ae[4][8];                                                            \
    _Pragma("unroll") for (int p = 0; p < 4; ++p) {                            \
      const uint4 v = *(const uint4*)&Bs16[buf_][p * 2][l * 8];                \
      ae[p][0] = bflo(v.x); ae[p][1] = bfhi(v.x);                              \
      ae[p][2] = bflo(v.y); ae[p][3] = bfhi(v.y);                              \
      ae[p][4] = bflo(v.z); ae[p][5] = bfhi(v.z);                              \
      ae[p][6] = bflo(v.w); ae[p][7] = bfhi(v.w);                              \
    }                                                                          \
    _Pragma("unroll") for (int jj = 0; jj < 6; ++jj) {                         \
      const int j_ = w * 6 + jj;                                               \
      const int jt_ = j_ >> 4, jlo_ = j_ & 15;                                 \
      const f32x4 ha = *(const f32x4*)&hs[buf_][0][jt_][jlo_][0];              \
      const f32x4 hb = *(const f32x4*)&hs[buf_][1][jt_][jlo_][0];              \
      const f32x4 h4 = ha + hb;                                                \
      _Pragma("unroll") for (int p = 0; p < 4; ++p) {                          \
        const float hv = h4[p];                                                \
        _Pragma("unroll") for (int e = 0; e < 8; ++e)                          \
            yv[jj][e] = fmaf(hv, ae[p][e], yv[jj][e]);                         \
      }                                                                        \
    }                                                                          \
  }

  STAGE(0);

  for (int t = 0; t < NBATCH; ++t) {
    asm volatile("s_waitcnt vmcnt(0)" ::: "memory");  // STAGE(t) resident
    asm volatile("s_waitcnt lgkmcnt(0)\n\ts_barrier" ::: "memory");  // A
    if (t + 1 < NBATCH) STAGE(t + 1);

    // cvt(t): rows[t&1] f32 -> Bs16[t&1] bf16. 16 elems/thread.
    {
      const int r_ = tid >> 5;
      const int c0 = (tid & 31) * 16;
      const float4 a = *(const float4*)&rows[t & 1][r_][c0];
      const float4 b = *(const float4*)&rows[t & 1][r_][c0 + 4];
      const float4 c = *(const float4*)&rows[t & 1][r_][c0 + 8];
      const float4 e = *(const float4*)&rows[t & 1][r_][c0 + 12];
      uint4 o0, o1;
      o0.x = pk2(a.x, a.y); o0.y = pk2(a.z, a.w);
      o0.z = pk2(b.x, b.y); o0.w = pk2(b.z, b.w);
      o1.x = pk2(c.x, c.y); o1.y = pk2(c.z, c.w);
      o1.z = pk2(e.x, e.y); o1.w = pk2(e.z, e.w);
      *(uint4*)&Bs16[t & 1][r_][c0] = o0;
      *(uint4*)&Bs16[t & 1][r_][c0 + 8] = o1;
    }

    if (t) Y_PHASE(t - 1);  // lagged y: (t-1)&1 buffers stable

    asm volatile("s_waitcnt lgkmcnt(0)\n\ts_barrier" ::: "memory");  // B

    // deg(t): wave w sums bf16 rows 2w, 2w+1 (lane's 8 s)
#pragma unroll
    for (int rr = 0; rr < 2; ++rr) {
      const uint4 v = *(const uint4*)&Bs16[t & 1][2 * w + rr][l * 8];
      dgv[0] += bflo(v.x); dgv[1] += bfhi(v.x);
      dgv[2] += bflo(v.y); dgv[3] += bfhi(v.y);
      dgv[4] += bflo(v.z); dgv[5] += bfhi(v.z);
      dgv[6] += bflo(v.w); dgv[7] += bfhi(v.w);
    }

    // h-MFMA(t): 16 x 16x16x32 (R7/R9-validated layout)
    {
      f32x4 acc = {0.f, 0.f, 0.f, 0.f};
#pragma unroll
      for (int ks = 0; ks < 16; ++ks) {
        const bf16x8 bfr =
            *(const bf16x8*)&Bs16[t & 1][pl * 2 + kh][ks * 32 + kg * 8];
        acc = __builtin_amdgcn_mfma_f32_16x16x32_bf16(gf[ks], bfr, acc, 0, 0, 0);
      }
      if (jl < 4) {
#pragma unroll
        for (int i = 0; i < 4; ++i) hs[t & 1][kh][mt][kg * 4 + i][jl] = acc[i];
      }
    }
  }

  asm volatile("s_waitcnt lgkmcnt(0)\n\ts_barrier" ::: "memory");
  Y_PHASE(NBATCH - 1);

  // y partials -> bf16 yp; deg partials -> degp f32
  ushort_t* ypb = yp + (size_t)(pc * D_DOM + d) * NJ * S_RES;
#pragma unroll
  for (int jj = 0; jj < 6; ++jj) {
    const int j = w * 6 + jj;
    uint4 o;
    o.x = pk2(yv[jj][0], yv[jj][1]);
    o.y = pk2(yv[jj][2], yv[jj][3]);
    o.z = pk2(yv[jj][4], yv[jj][5]);
    o.w = pk2(yv[jj][6], yv[jj][7]);
    *(uint4*)(ypb + (size_t)j * S_RES + l * 8) = o;
  }
  {
    float* dp = degp + (((size_t)(d * NPC + pc)) * 4 + w) * S_RES + l * 8;
    *(float4*)dp = make_float4(dgv[0], dgv[1], dgv[2], dgv[3]);
    *(float4*)(dp + 4) = make_float4(dgv[4], dgv[5], dgv[6], dgv[7]);
  }
}

// ---------------------------------------------------------------------------
// Kernel D01 (kD0 folded into kD1, PARALLEL — R12 lesson: keep 1536 blocks):
// grid (24, 64); each block recomputes its domain's rdeg (L2-resident,
// 24x duplicated but parallel), then pc-sum + max-pool for its (d, j).
// ---------------------------------------------------------------------------
__global__ __launch_bounds__(256) void kD01_pool(const ushort_t* __restrict__ yp,
                                                 const float* __restrict__ degp,
                                                 float* __restrict__ pool) {
  const int j = blockIdx.x;
  const int d = blockIdx.y;
  const int tid = threadIdx.x;
  __shared__ float wmax[4];

  float dg0 = 0.f, dg1 = 0.f;
  const float* base = degp + (size_t)d * NPC * 4 * S_RES;
#pragma unroll 8
  for (int k = 0; k < NPC * 4; ++k) {
    const float2 dv = *(const float2*)(base + (size_t)k * S_RES + 2 * tid);
    dg0 += dv.x;
    dg1 += dv.y;
  }

  float v0 = 0.f, v1 = 0.f;
#pragma unroll
  for (int pc = 0; pc < NPC; ++pc) {
    const ushort2 yv =
        *(const ushort2*)(yp + ((size_t)(pc * D_DOM + d) * NJ + j) * S_RES + 2 * tid);
    v0 += bf2f(yv.x);
    v1 += bf2f(yv.y);
  }
  float m = fmaxf(v0 / dg0, v1 / dg1);
#pragma unroll
  for (int mask = 32; mask; mask >>= 1) m = fmaxf(m, __shfl_xor(m, mask));
  if ((tid & 63) == 0) wmax[tid >> 6] = m;
  __syncthreads();
  if (tid == 0)
    pool[d * NJ + j] = fmaxf(fmaxf(wmax[0], wmax[1]), fmaxf(wmax[2], wmax[3]));
}

// ---------------------------------------------------------------------------
// Kernel D2: out = sigmoid(pool @ w_combine). 1 block.
// ---------------------------------------------------------------------------
__global__ __launch_bounds__(128) void kD2_out(const float* __restrict__ pool,
                                               const float* __restrict__ wcomb,
                                               float* __restrict__ out) {
  const int t = threadIdx.x;
  if (t < D_DOM * NB) {
    const int d = t >> 1, b = t & 1;
    float sc = 0.f;
#pragma unroll
    for (int f = 0; f < NF; ++f) sc = fmaf(pool[d * NJ + b * NF + f], wcomb[f], sc);
    out[t] = 1.0f / (1.0f + expf(-sc));
  }
}

// ---------------------------------------------------------------------------
extern "C" void kernel_launch(void* const* d_in, const int* in_sizes, int n_in,
                              void* d_out, int out_size, void* d_ws, size_t ws_size,
                              hipStream_t stream) {
  const float* aa = (const float*)d_in[0];
  const float* adjs = (const float*)d_in[1];
  const float* wconv = (const float*)d_in[2];
  const float* wcomb = (const float*)d_in[3];
  float* out = (float*)d_out;
  char* wsb = (char*)d_ws;

  // ws layout (bytes):
  //   g    bf16 [64][24][1024] @ 0          = 3,145,728
  //   yp   bf16 [8*64*24*512]  @ 3,145,728  = 12,582,912
  //   degp f32  [64*8*4*512]   @ 15,728,640 = 4,194,304
  //   pool f32  [64*24]        @ 19,922,944 = 6,144     (total ~19.9 MB)
  ushort_t* g = (ushort_t*)wsb;
  ushort_t* yp = (ushort_t*)(wsb + 3145728);
  float* degp = (float*)(wsb + 15728640);
  float* pool = (float*)(wsb + 19922944);

  kA_g<<<dim3(128, 2), dim3(256), 0, stream>>>(aa, wconv, g);
  kB_main<<<dim3(512), dim3(256), 0, stream>>>(adjs, g, yp, degp);
  kD01_pool<<<dim3(24, 64), dim3(256), 0, stream>>>(yp, degp, pool);
  kD2_out<<<dim3(1), dim3(128), 0, stream>>>(pool, wcomb, out);
}

// Round 14
// 94.417 us; speedup vs baseline: 1.1273x; 1.1273x over previous
//
#include <hip/hip_runtime.h>
#include <math.h>

// Problem constants
#define D_DOM 64
#define S_RES 512
#define R_ROWS 2048
#define NAA 20
#define NF 12
#define NB 2
#define NJ 24       // NB*NF
#define NPC 8       // p-chunks per domain (256 rows each)
#define BROWS 8     // rows per stage batch (16 KB f32, 4 p)
#define NBATCH 32   // batches per block (256 rows)
#define BSTR 520    // bf16 row stride (+8 pad) — R13's 512 regressed; keep 520

typedef unsigned short ushort_t;
typedef unsigned int uint_t;
typedef short bf16x8 __attribute__((ext_vector_type(8)));   // 8 bf16 = 4 VGPR
typedef float f32x4 __attribute__((ext_vector_type(4)));

// bf16 helpers (RNE), dependency-free — validated R4-R13
__device__ __forceinline__ ushort_t f2bf(float x) {
  uint_t u = __float_as_uint(x);
  uint_t r = u + 0x7FFFu + ((u >> 16) & 1u);
  return (ushort_t)(r >> 16);
}
__device__ __forceinline__ float bflo(uint_t u) { return __uint_as_float(u << 16); }
__device__ __forceinline__ float bfhi(uint_t u) { return __uint_as_float(u & 0xFFFF0000u); }
__device__ __forceinline__ float bf2f(ushort_t h) {
  return __uint_as_float(((uint_t)h) << 16);
}
__device__ __forceinline__ uint_t pk2(float a, float b) {
  return (uint_t)f2bf(a) | ((uint_t)f2bf(b) << 16);
}

// Direct global->LDS DMA, 16 B/lane (dest wave-uniform base).
__device__ __forceinline__ void gload_lds16(const float* g, float* l) {
  __builtin_amdgcn_global_load_lds((const __attribute__((address_space(1))) void*)g,
                                   (__attribute__((address_space(3))) void*)l,
                                   16, 0, 0);
}

// ---------------------------------------------------------------------------
// Kernel A: G[d][j][k] bf16 (k<512: g0[j,s]; k>=512: g1[j,s]). grid (128,2).
// ---------------------------------------------------------------------------
__global__ __launch_bounds__(256) void kA_g(const float* __restrict__ aa,
                                            const float* __restrict__ wconv,
                                            ushort_t* __restrict__ g) {
  __shared__ float ws[NF * NAA * 2];
  const int tid = threadIdx.x;
  for (int i = tid; i < NF * NAA * 2; i += 256) ws[i] = wconv[i];
  __syncthreads();
  const int pos = blockIdx.x * 256 + tid;  // d*512 + s
  const int b = blockIdx.y;
  float av[NAA];
#pragma unroll
  for (int c = 0; c < NAA; ++c)
    av[c] = aa[(size_t)(b * NAA + c) * (D_DOM * S_RES) + pos];
  const int d = pos >> 9;
  const int s = pos & 511;
#pragma unroll
  for (int f = 0; f < NF; ++f) {
    float s0 = 0.f, s1 = 0.f;
#pragma unroll
    for (int c = 0; c < NAA; ++c) {
      const float a = av[c];
      s0 = fmaf(a, ws[(f * NAA + c) * 2 + 0], s0);
      s1 = fmaf(a, ws[(f * NAA + c) * 2 + 1], s1);
    }
    const int j = b * NF + f;
    g[((size_t)(d * NJ + j)) * 1024 + s] = f2bf(s0);
    g[((size_t)(d * NJ + j)) * 1024 + 512 + s] = f2bf(s1);
  }
}

// ---------------------------------------------------------------------------
// Kernel B — R10 champion VERBATIM (94.7 us). 2-barrier lagged-y pipeline,
// gload_lds dbuf staging, MFMA h-GEMM, VALU y-phase.
// Local-optimum evidence: R11 super-batch (-30), R12 fused tail (-10),
// R13 BSTR=512 + parallel-deg tail (-12) all regressed. Do not perturb.
// ---------------------------------------------------------------------------
__global__ __launch_bounds__(256) void kB_main(const float* __restrict__ adjs,
                                               const ushort_t* __restrict__ g,
                                               ushort_t* __restrict__ yp,
                                               float* __restrict__ degp) {
  const int tid = threadIdx.x;
  const int w = tid >> 6;   // 0..3
  const int l = tid & 63;
  const int d = blockIdx.x >> 3;
  const int pc = blockIdx.x & 7;

  const int mt = w & 1, kh = w >> 1;
  const int jl = l & 15, kg = l >> 4;
  const int pl = jl & 3;  // B-frag p (cols 4-15 duplicate 0-3, ignored)

  __shared__ float rows[2][BROWS][S_RES];                  // 32 KB f32 (dbuf)
  __shared__ __align__(16) ushort_t Bs16[2][BROWS][BSTR];  // 16.25 KB (dbuf)
  __shared__ __align__(16) float hs[2][2][2][16][4];       // 4 KB

  const float* ablk = adjs + ((size_t)d * R_ROWS + (size_t)pc * 256) * S_RES;

  // A-frags: wave's (mt, kh): 16 ksteps x 8 bf16 (loop-invariant, 64 VGPR)
  bf16x8 gf[16];
  {
    const int j_a = mt * 16 + jl;
    const bool valid = (j_a < NJ);
    const ushort_t* gr =
        g + ((size_t)(d * NJ + (valid ? j_a : 0))) * 1024 + kh * 512 + kg * 8;
    const bf16x8 z = {};
#pragma unroll
    for (int ks = 0; ks < 16; ++ks) {
      bf16x8 v = *(const bf16x8*)(gr + ks * 32);
      gf[ks] = valid ? v : z;
    }
  }

  float yv[6][8];
#pragma unroll
  for (int jj = 0; jj < 6; ++jj)
#pragma unroll
    for (int e = 0; e < 8; ++e) yv[jj][e] = 0.f;
  float dgv[8];
#pragma unroll
  for (int e = 0; e < 8; ++e) dgv[e] = 0.f;

#define STAGE(T)                                                               \
  {                                                                            \
    _Pragma("unroll")                                                          \
    for (int q = 0; q < 4; ++q) {                                              \
      const int u_ = w * 4 + q;                                                \
      const int row_ = u_ >> 1;                                                \
      const int half_ = u_ & 1;                                                \
      gload_lds16(ablk + ((size_t)((T)*BROWS + row_)) * S_RES + half_ * 256 +  \
                      l * 4,                                                   \
                  &rows[(T) & 1][row_][half_ * 256]);                          \
    }                                                                          \
  }

#define Y_PHASE(TT)                                                            \
  {                                                                            \
    const int buf_ = (TT) & 1;                                                 \
    float ae[4][8];                                                            \
    _Pragma("unroll") for (int p = 0; p < 4; ++p) {                            \
      const uint4 v = *(const uint4*)&Bs16[buf_][p * 2][l * 8];                \
      ae[p][0] = bflo(v.x); ae[p][1] = bfhi(v.x);                              \
      ae[p][2] = bflo(v.y); ae[p][3] = bfhi(v.y);                              \
      ae[p][4] = bflo(v.z); ae[p][5] = bfhi(v.z);                              \
      ae[p][6] = bflo(v.w); ae[p][7] = bfhi(v.w);                              \
    }                                                                          \
    _Pragma("unroll") for (int jj = 0; jj < 6; ++jj) {                         \
      const int j_ = w * 6 + jj;                                               \
      const int jt_ = j_ >> 4, jlo_ = j_ & 15;                                 \
      const f32x4 ha = *(const f32x4*)&hs[buf_][0][jt_][jlo_][0];              \
      const f32x4 hb = *(const f32x4*)&hs[buf_][1][jt_][jlo_][0];              \
      const f32x4 h4 = ha + hb;                                                \
      _Pragma("unroll") for (int p = 0; p < 4; ++p) {                          \
        const float hv = h4[p];                                                \
        _Pragma("unroll") for (int e = 0; e < 8; ++e)                          \
            yv[jj][e] = fmaf(hv, ae[p][e], yv[jj][e]);                         \
      }                                                                        \
    }                                                                          \
  }

  STAGE(0);

  for (int t = 0; t < NBATCH; ++t) {
    asm volatile("s_waitcnt vmcnt(0)" ::: "memory");  // STAGE(t) resident
    asm volatile("s_waitcnt lgkmcnt(0)\n\ts_barrier" ::: "memory");  // A
    if (t + 1 < NBATCH) STAGE(t + 1);

    // cvt(t): rows[t&1] f32 -> Bs16[t&1] bf16. 16 elems/thread.
    {
      const int r_ = tid >> 5;
      const int c0 = (tid & 31) * 16;
      const float4 a = *(const float4*)&rows[t & 1][r_][c0];
      const float4 b = *(const float4*)&rows[t & 1][r_][c0 + 4];
      const float4 c = *(const float4*)&rows[t & 1][r_][c0 + 8];
      const float4 e = *(const float4*)&rows[t & 1][r_][c0 + 12];
      uint4 o0, o1;
      o0.x = pk2(a.x, a.y); o0.y = pk2(a.z, a.w);
      o0.z = pk2(b.x, b.y); o0.w = pk2(b.z, b.w);
      o1.x = pk2(c.x, c.y); o1.y = pk2(c.z, c.w);
      o1.z = pk2(e.x, e.y); o1.w = pk2(e.z, e.w);
      *(uint4*)&Bs16[t & 1][r_][c0] = o0;
      *(uint4*)&Bs16[t & 1][r_][c0 + 8] = o1;
    }

    if (t) Y_PHASE(t - 1);  // lagged y: (t-1)&1 buffers stable

    asm volatile("s_waitcnt lgkmcnt(0)\n\ts_barrier" ::: "memory");  // B

    // deg(t): wave w sums bf16 rows 2w, 2w+1 (lane's 8 s)
#pragma unroll
    for (int rr = 0; rr < 2; ++rr) {
      const uint4 v = *(const uint4*)&Bs16[t & 1][2 * w + rr][l * 8];
      dgv[0] += bflo(v.x); dgv[1] += bfhi(v.x);
      dgv[2] += bflo(v.y); dgv[3] += bfhi(v.y);
      dgv[4] += bflo(v.z); dgv[5] += bfhi(v.z);
      dgv[6] += bflo(v.w); dgv[7] += bfhi(v.w);
    }

    // h-MFMA(t): 16 x 16x16x32 (R7/R9-validated layout)
    {
      f32x4 acc = {0.f, 0.f, 0.f, 0.f};
#pragma unroll
      for (int ks = 0; ks < 16; ++ks) {
        const bf16x8 bfr =
            *(const bf16x8*)&Bs16[t & 1][pl * 2 + kh][ks * 32 + kg * 8];
        acc = __builtin_amdgcn_mfma_f32_16x16x32_bf16(gf[ks], bfr, acc, 0, 0, 0);
      }
      if (jl < 4) {
#pragma unroll
        for (int i = 0; i < 4; ++i) hs[t & 1][kh][mt][kg * 4 + i][jl] = acc[i];
      }
    }
  }

  asm volatile("s_waitcnt lgkmcnt(0)\n\ts_barrier" ::: "memory");
  Y_PHASE(NBATCH - 1);

  // y partials -> bf16 yp; deg partials -> degp f32
  ushort_t* ypb = yp + (size_t)(pc * D_DOM + d) * NJ * S_RES;
#pragma unroll
  for (int jj = 0; jj < 6; ++jj) {
    const int j = w * 6 + jj;
    uint4 o;
    o.x = pk2(yv[jj][0], yv[jj][1]);
    o.y = pk2(yv[jj][2], yv[jj][3]);
    o.z = pk2(yv[jj][4], yv[jj][5]);
    o.w = pk2(yv[jj][6], yv[jj][7]);
    *(uint4*)(ypb + (size_t)j * S_RES + l * 8) = o;
  }
  {
    float* dp = degp + (((size_t)(d * NPC + pc)) * 4 + w) * S_RES + l * 8;
    *(float4*)dp = make_float4(dgv[0], dgv[1], dgv[2], dgv[3]);
    *(float4*)(dp + 4) = make_float4(dgv[4], dgv[5], dgv[6], dgv[7]);
  }
}

// ---------------------------------------------------------------------------
// Kernel D0: rdeg[d][s] = 1 / sum over 32 partials (8 pc x 4 w).
// R10 tail verbatim — R12's fusion (serial j-loop) and R13's parallel
// deg-recompute both regressed; this 3-kernel parallel tail is fastest.
// ---------------------------------------------------------------------------
__global__ __launch_bounds__(256) void kD0_rdeg(const float* __restrict__ degp,
                                                float* __restrict__ rdeg) {
  const int d = blockIdx.x;
  const int tid = threadIdx.x;
  float dg0 = 0.f, dg1 = 0.f;
  const float* base = degp + (size_t)d * NPC * 4 * S_RES;
#pragma unroll 8
  for (int k = 0; k < NPC * 4; ++k) {
    const float2 dv = *(const float2*)(base + (size_t)k * S_RES + 2 * tid);
    dg0 += dv.x;
    dg1 += dv.y;
  }
  *(float2*)(rdeg + (size_t)d * S_RES + 2 * tid) = make_float2(1.f / dg0, 1.f / dg1);
}

// ---------------------------------------------------------------------------
// Kernel D1: pooled[d][j] = max_s (sum_pc yp) * rdeg.  grid (24, 64).
// ---------------------------------------------------------------------------
__global__ __launch_bounds__(256) void kD1_pool(const ushort_t* __restrict__ yp,
                                                const float* __restrict__ rdeg,
                                                float* __restrict__ pool) {
  const int j = blockIdx.x;
  const int d = blockIdx.y;
  const int tid = threadIdx.x;
  __shared__ float wmax[4];

  float v0 = 0.f, v1 = 0.f;
#pragma unroll
  for (int pc = 0; pc < NPC; ++pc) {
    const ushort2 yv =
        *(const ushort2*)(yp + ((size_t)(pc * D_DOM + d) * NJ + j) * S_RES + 2 * tid);
    v0 += __uint_as_float((uint_t)yv.x << 16);
    v1 += __uint_as_float((uint_t)yv.y << 16);
  }
  const float2 rv = *(const float2*)(rdeg + (size_t)d * S_RES + 2 * tid);
  float m = fmaxf(v0 * rv.x, v1 * rv.y);
#pragma unroll
  for (int mask = 32; mask; mask >>= 1) m = fmaxf(m, __shfl_xor(m, mask));
  if ((tid & 63) == 0) wmax[tid >> 6] = m;
  __syncthreads();
  if (tid == 0)
    pool[d * NJ + j] = fmaxf(fmaxf(wmax[0], wmax[1]), fmaxf(wmax[2], wmax[3]));
}

// ---------------------------------------------------------------------------
// Kernel D2: out = sigmoid(pool @ w_combine). 1 block.
// ---------------------------------------------------------------------------
__global__ __launch_bounds__(128) void kD2_out(const float* __restrict__ pool,
                                               const float* __restrict__ wcomb,
                                               float* __restrict__ out) {
  const int t = threadIdx.x;
  if (t < D_DOM * NB) {
    const int d = t >> 1, b = t & 1;
    float sc = 0.f;
#pragma unroll
    for (int f = 0; f < NF; ++f) sc = fmaf(pool[d * NJ + b * NF + f], wcomb[f], sc);
    out[t] = 1.0f / (1.0f + expf(-sc));
  }
}

// ---------------------------------------------------------------------------
extern "C" void kernel_launch(void* const* d_in, const int* in_sizes, int n_in,
                              void* d_out, int out_size, void* d_ws, size_t ws_size,
                              hipStream_t stream) {
  const float* aa = (const float*)d_in[0];
  const float* adjs = (const float*)d_in[1];
  const float* wconv = (const float*)d_in[2];
  const float* wcomb = (const float*)d_in[3];
  float* out = (float*)d_out;
  char* wsb = (char*)d_ws;

  // ws layout (bytes):
  //   g    bf16 [64][24][1024] @ 0          = 3,145,728
  //   yp   bf16 [8*64*24*512]  @ 3,145,728  = 12,582,912
  //   degp f32  [64*8*4*512]   @ 15,728,640 = 4,194,304
  //   rdeg f32  [64*512]       @ 19,922,944 = 131,072
  //   pool f32  [64*24]        @ 20,054,016 = 6,144     (total ~20.1 MB)
  ushort_t* g = (ushort_t*)wsb;
  ushort_t* yp = (ushort_t*)(wsb + 3145728);
  float* degp = (float*)(wsb + 15728640);
  float* rdeg = (float*)(wsb + 19922944);
  float* pool = (float*)(wsb + 20054016);

  kA_g<<<dim3(128, 2), dim3(256), 0, stream>>>(aa, wconv, g);
  kB_main<<<dim3(512), dim3(256), 0, stream>>>(adjs, g, yp, degp);
  kD0_rdeg<<<dim3(64), dim3(256), 0, stream>>>(degp, rdeg);
  kD1_pool<<<dim3(24, 64), dim3(256), 0, stream>>>(yp, rdeg, pool);
  kD2_out<<<dim3(1), dim3(128), 0, stream>>>(pool, wcomb, out);
}